// Round 1
// baseline (137.660 us; speedup 1.0000x reference)
//
#include <hip/hip_runtime.h>

// SparseFlowModel: per-batch voxel-block neighbor queries.
// coords: [4, 2048, 3] int32 in [0,64). Outputs (concat flat, float32):
//   prior [4,2048,4096]  then  occ [4,2048,26]
//
// Strategy: per-batch occupancy bitmap over the 64^3 domain (8192 u32 words
// = 32KB/batch) in d_ws. Hash in the reference is injective over [-1,64]^3,
// so membership == coord-triple membership; out-of-range neighbors are never
// present. Three stream-ordered steps: memset ws -> scatter bits -> compute.

#define B 4
#define N 2048
#define BM_WORDS 8192                 // 64*64*64 / 32 per batch
#define PRIOR_ELEMS (4ull * 2048ull * 4096ull)   // 33554432

static __device__ __constant__ int NB_OFF[26][3] = {
    {-1,0,0},{1,0,0},{0,-1,0},{0,1,0},{0,0,-1},{0,0,1},
    {-1,-1,0},{-1,1,0},{1,-1,0},{1,1,0},
    {-1,0,-1},{-1,0,1},{1,0,-1},{1,0,1},
    {0,-1,-1},{0,-1,1},{0,1,-1},{0,1,1},
    {-1,-1,-1},{-1,-1,1},{-1,1,-1},{-1,1,1},
    {1,-1,-1},{1,-1,1},{1,1,-1},{1,1,1}
};

__device__ __forceinline__ bool bm_test(const unsigned* bm, int x, int y, int z) {
    // valid domain is [0,64); neighbors can be -1 or 64 -> always absent.
    if (((x | y | z) & ~63) != 0) return false;   // catches negatives and >=64
    unsigned idx = ((unsigned)x << 12) | ((unsigned)y << 6) | (unsigned)z;
    return (bm[idx >> 5] >> (idx & 31u)) & 1u;
}

__global__ void scatter_bits(const int* __restrict__ coords, unsigned* __restrict__ bm) {
    int id = blockIdx.x * blockDim.x + threadIdx.x;   // 0..8191 (B*N)
    if (id >= B * N) return;
    int b = id >> 11;
    int x = coords[id * 3 + 0];
    int y = coords[id * 3 + 1];
    int z = coords[id * 3 + 2];
    unsigned idx = ((unsigned)x << 12) | ((unsigned)y << 6) | (unsigned)z;
    atomicOr(&bm[b * BM_WORDS + (idx >> 5)], 1u << (idx & 31u));
}

__global__ void __launch_bounds__(256)
compute_outputs(const int* __restrict__ coords, const unsigned* __restrict__ bm,
                float* __restrict__ out) {
    int pid = blockIdx.x;             // 0..8191 == b*2048 + n
    int tid = threadIdx.x;            // 0..255
    int b = pid >> 11;
    const unsigned* bmb = bm + b * BM_WORDS;

    int x = coords[pid * 3 + 0];
    int y = coords[pid * 3 + 1];
    int z = coords[pid * 3 + 2];

    // 6 face-neighbor existence bits (bitmap is L1/L2 resident)
    bool nxm = bm_test(bmb, x - 1, y, z);
    bool nxp = bm_test(bmb, x + 1, y, z);
    bool nym = bm_test(bmb, x, y - 1, z);
    bool nyp = bm_test(bmb, x, y + 1, z);
    bool nzm = bm_test(bmb, x, y, z - 1);
    bool nzp = bm_test(bmb, x, y, z + 1);

    const float inv15 = 1.0f / 15.0f;
    float4* outp = (float4*)(out + (size_t)pid * 4096);

    // 4096 voxels / block, 4 float4 per thread; v = ix*256 + iy*16 + iz
    #pragma unroll
    for (int j = 0; j < 4; ++j) {
        int v4 = j * 256 + tid;       // float4 index; v = v4*4
        int v = v4 * 4;
        int ix = (v >> 8) & 15;
        int iy = (v >> 4) & 15;
        int iz0 = v & 15;             // multiple of 4; iz = iz0..iz0+3
        float gx = ix * inv15;
        float gy = iy * inv15;
        float m = 1.0f;
        if (!nxm) m = fminf(m, gx);
        if (!nxp) m = fminf(m, 1.0f - gx);
        if (!nym) m = fminf(m, gy);
        if (!nyp) m = fminf(m, 1.0f - gy);
        float r[4];
        #pragma unroll
        for (int k = 0; k < 4; ++k) {
            float gz = (iz0 + k) * inv15;
            float mm = m;
            if (!nzm) mm = fminf(mm, gz);
            if (!nzp) mm = fminf(mm, 1.0f - gz);
            r[k] = mm;
        }
        outp[v4] = make_float4(r[0], r[1], r[2], r[3]);
    }

    // occ [B,N,26] after prior
    if (tid < 26) {
        bool hit = bm_test(bmb, x + NB_OFF[tid][0], y + NB_OFF[tid][1], z + NB_OFF[tid][2]);
        out[PRIOR_ELEMS + (size_t)pid * 26 + tid] = hit ? 1.0f : 0.0f;
    }
}

extern "C" void kernel_launch(void* const* d_in, const int* in_sizes, int n_in,
                              void* d_out, int out_size, void* d_ws, size_t ws_size,
                              hipStream_t stream) {
    const int* coords = (const int*)d_in[0];
    float* out = (float*)d_out;
    unsigned* bm = (unsigned*)d_ws;

    // ws is re-poisoned to 0xAA each call: zero the bitmap every launch.
    hipMemsetAsync(bm, 0, (size_t)B * BM_WORDS * sizeof(unsigned), stream);

    scatter_bits<<<(B * N + 255) / 256, 256, 0, stream>>>(coords, bm);
    compute_outputs<<<B * N, 256, 0, stream>>>(coords, bm, out);
}

// Round 2
// 137.210 us; speedup vs baseline: 1.0033x; 1.0033x over previous
//
#include <hip/hip_runtime.h>

// SparseFlowModel fused single-kernel version.
// coords: [4, 2048, 3] int32 in [0,64). Outputs (concat flat, float32):
//   prior [4,2048,4096]  then  occ [4,2048,26]
//
// The reference hash (x*100003 + y*1009 + z) is injective over [-1,64]^3,
// so neighbor matching == exact coord-triple membership, and out-of-range
// neighbors (-1 or 64) are never present.
//
// One dispatch: each block serves PPB=8 consecutive points of one batch.
// It rebuilds the batch's 64^3 occupancy bitmap (8192 u32 = 32 KB) in LDS
// (zero + 2048 LDS atomicOr; coords are L2-resident), then emits the
// 8*16KB prior tiles (coalesced float4) and 8*26 occ flags.
// LDS 32KB -> 4 blocks/CU; grid 1024 = 4 blocks/CU exactly, 16 waves/CU.

#define B 4
#define N 2048
#define PPB 8
#define BLOCKS_PER_BATCH (N / PPB)          // 256
#define BM_WORDS 8192                       // 64^3 / 32
#define PRIOR_ELEMS (4ull * 2048ull * 4096ull)

static __device__ __constant__ int NB_OFF[26][3] = {
    {-1,0,0},{1,0,0},{0,-1,0},{0,1,0},{0,0,-1},{0,0,1},
    {-1,-1,0},{-1,1,0},{1,-1,0},{1,1,0},
    {-1,0,-1},{-1,0,1},{1,0,-1},{1,0,1},
    {0,-1,-1},{0,-1,1},{0,1,-1},{0,1,1},
    {-1,-1,-1},{-1,-1,1},{-1,1,-1},{-1,1,1},
    {1,-1,-1},{1,-1,1},{1,1,-1},{1,1,1}
};

__device__ __forceinline__ bool bm_test(const unsigned* bm, int x, int y, int z) {
    if (((x | y | z) & ~63) != 0) return false;   // negatives or >=64 -> absent
    unsigned idx = ((unsigned)x << 12) | ((unsigned)y << 6) | (unsigned)z;
    return (bm[idx >> 5] >> (idx & 31u)) & 1u;
}

__global__ void __launch_bounds__(256, 4)
fused_kernel(const int* __restrict__ coords, float* __restrict__ out) {
    __shared__ unsigned bm[BM_WORDS];
    __shared__ unsigned char fex[PPB][6];   // face-neighbor existence per point

    const int tid = threadIdx.x;
    const int blk = blockIdx.x;
    const int b = blk / BLOCKS_PER_BATCH;
    const int p0 = (blk % BLOCKS_PER_BATCH) * PPB;   // first local point index
    const int* cb = coords + b * N * 3;

    // 1) zero the bitmap (32 words/thread)
    for (int i = tid; i < BM_WORDS; i += 256) bm[i] = 0u;
    __syncthreads();

    // 2) scatter all 2048 batch points into the LDS bitmap (8/thread)
    for (int i = tid; i < N; i += 256) {
        int x = cb[3 * i + 0];
        int y = cb[3 * i + 1];
        int z = cb[3 * i + 2];
        unsigned idx = ((unsigned)x << 12) | ((unsigned)y << 6) | (unsigned)z;
        atomicOr(&bm[idx >> 5], 1u << (idx & 31u));
    }
    __syncthreads();

    // 3a) face-existence bits for this block's 8 points (48 threads)
    if (tid < PPB * 6) {
        int p = tid / 6, f = tid % 6;
        int x = cb[3 * (p0 + p) + 0];
        int y = cb[3 * (p0 + p) + 1];
        int z = cb[3 * (p0 + p) + 2];
        fex[p][f] = bm_test(bm, x + NB_OFF[f][0], y + NB_OFF[f][1], z + NB_OFF[f][2]) ? 1 : 0;
    }
    // 3b) occ flags: 8*26 = 208 threads, contiguous/coalesced store
    if (tid < PPB * 26) {
        int p = tid / 26, k = tid % 26;
        int x = cb[3 * (p0 + p) + 0];
        int y = cb[3 * (p0 + p) + 1];
        int z = cb[3 * (p0 + p) + 2];
        float hit = bm_test(bm, x + NB_OFF[k][0], y + NB_OFF[k][1], z + NB_OFF[k][2]) ? 1.0f : 0.0f;
        out[PRIOR_ELEMS + (size_t)(b * N + p0) * 26 + tid] = hit;
    }
    __syncthreads();

    // 4) prior tiles: 8 points x 4096 voxels, 4 float4/thread/point.
    //    v = ix*256 + iy*16 + iz (z fastest), dist = idx/15.
    const float inv15 = 1.0f / 15.0f;
    #pragma unroll
    for (int p = 0; p < PPB; ++p) {
        bool nxm = fex[p][0], nxp = fex[p][1];
        bool nym = fex[p][2], nyp = fex[p][3];
        bool nzm = fex[p][4], nzp = fex[p][5];
        float4* outp = (float4*)(out + (size_t)(b * N + p0 + p) * 4096);
        #pragma unroll
        for (int j = 0; j < 4; ++j) {
            int v4 = j * 256 + tid;     // float4 index within the 4096-voxel tile
            int v = v4 * 4;
            float gx = (float)((v >> 8) & 15) * inv15;
            float gy = (float)((v >> 4) & 15) * inv15;
            int iz0 = v & 15;
            float m = 1.0f;
            if (!nxm) m = fminf(m, gx);
            if (!nxp) m = fminf(m, 1.0f - gx);
            if (!nym) m = fminf(m, gy);
            if (!nyp) m = fminf(m, 1.0f - gy);
            float r[4];
            #pragma unroll
            for (int k = 0; k < 4; ++k) {
                float gz = (float)(iz0 + k) * inv15;
                float mm = m;
                if (!nzm) mm = fminf(mm, gz);
                if (!nzp) mm = fminf(mm, 1.0f - gz);
                r[k] = mm;
            }
            outp[v4] = make_float4(r[0], r[1], r[2], r[3]);
        }
    }
}

extern "C" void kernel_launch(void* const* d_in, const int* in_sizes, int n_in,
                              void* d_out, int out_size, void* d_ws, size_t ws_size,
                              hipStream_t stream) {
    const int* coords = (const int*)d_in[0];
    float* out = (float*)d_out;
    fused_kernel<<<B * N / PPB, 256, 0, stream>>>(coords, out);
}